// Round 1
// baseline (4045.749 us; speedup 1.0000x reference)
//
#include <hip/hip_runtime.h>

#define N_NODES 100000
#define N_EDGES 1600000
#define IN_F    128
#define NEG_SLOPE 0.2f

// ---------------------------------------------------------------------------
// GEMM: out(nrows x F) = A(nrows x 128) @ W(128 x F)
// Block: 256 threads, 64 rows per block. A-tile staged in LDS; W read via L2
// (only 64KB, shared by all blocks). Register blocking: RPT rows x 4 cols.
// ---------------------------------------------------------------------------
template<int F>
__global__ __launch_bounds__(256) void gemm_feat(const float* __restrict__ A,
                                                 const float* __restrict__ W,
                                                 float* __restrict__ out,
                                                 int nrows) {
    constexpr int BM  = 64;
    constexpr int CG  = F / 4;              // column groups of 4
    constexpr int RPT = (BM * CG) / 256;    // rows per thread
    __shared__ float sH[BM][IN_F];

    const int t    = threadIdx.x;
    const int row0 = blockIdx.x * BM;

    // stage A tile (64 x 128 f32 = 32 KB), 8 float4 per thread
#pragma unroll
    for (int i = 0; i < (BM * IN_F) / (256 * 4); ++i) {
        int e4 = i * 256 + t;
        int r  = (e4 * 4) >> 7;
        int c  = (e4 * 4) & 127;
        float4 v = make_float4(0.f, 0.f, 0.f, 0.f);
        int gr = row0 + r;
        if (gr < nrows) v = *(const float4*)(A + (size_t)gr * IN_F + c);
        *(float4*)(&sH[r][c]) = v;
    }
    __syncthreads();

    const int tx  = t % CG;
    const int ty  = t / CG;
    const int col = tx * 4;

    float4 acc[RPT];
#pragma unroll
    for (int i = 0; i < RPT; ++i) acc[i] = make_float4(0.f, 0.f, 0.f, 0.f);

    for (int k = 0; k < IN_F; ++k) {
        float4 b = *(const float4*)(W + k * F + col);
#pragma unroll
        for (int i = 0; i < RPT; ++i) {
            float a = sH[ty * RPT + i][k];
            acc[i].x += a * b.x;
            acc[i].y += a * b.y;
            acc[i].z += a * b.z;
            acc[i].w += a * b.w;
        }
    }

#pragma unroll
    for (int i = 0; i < RPT; ++i) {
        int r = row0 + ty * RPT + i;
        if (r < nrows) *(float4*)(out + (size_t)r * F + col) = acc[i];
    }
}

// ---------------------------------------------------------------------------
// el/er: per (node, head) dot of feat row with al/ar.
// ---------------------------------------------------------------------------
__global__ __launch_bounds__(256) void eler_kernel(const float* __restrict__ feat,
                                                   const float* __restrict__ al,
                                                   const float* __restrict__ ar,
                                                   float* __restrict__ el,
                                                   float* __restrict__ er,
                                                   int nh_total, int H, int dim) {
    int g = blockIdx.x * blockDim.x + threadIdx.x;
    if (g >= nh_total) return;
    const float* f  = feat + (size_t)g * dim;
    const float* a1 = al + (g % H) * dim;
    const float* a2 = ar + (g % H) * dim;
    float s1 = 0.f, s2 = 0.f;
    for (int d = 0; d < dim; d += 4) {
        float4 v = *(const float4*)(f + d);
        float4 x = *(const float4*)(a1 + d);
        float4 y = *(const float4*)(a2 + d);
        s1 += v.x * x.x + v.y * x.y + v.z * x.z + v.w * x.w;
        s2 += v.x * y.x + v.y * y.y + v.z * y.z + v.w * y.w;
    }
    el[g] = s1;
    er[g] = s2;
}

// ---------------------------------------------------------------------------
// Edge pass A: den[dst,h] += exp(leaky(el[src,h] + er[dst,h])). Thread/edge.
// (Max-subtraction skipped: |e| is O(1) here, alpha = ex/den is invariant.)
// ---------------------------------------------------------------------------
template<int H>
__global__ __launch_bounds__(256) void edge_softmax_den(const int* __restrict__ src,
                                                        const int* __restrict__ dst,
                                                        const float* __restrict__ el,
                                                        const float* __restrict__ er,
                                                        float* __restrict__ den,
                                                        int nE) {
    int e = blockIdx.x * blockDim.x + threadIdx.x;
    if (e >= nE) return;
    int s = src[e], d = dst[e];
#pragma unroll
    for (int h = 0; h < H; ++h) {
        float v = el[s * H + h] + er[d * H + h];
        v = v > 0.f ? v : NEG_SLOPE * v;
        atomicAdd(&den[d * H + h], expf(v));
    }
}

// ---------------------------------------------------------------------------
// Edge pass B (H=4, D=32): one wave per edge, each lane handles 2 of the 128
// feature floats. alpha recomputed from el/er/den (all L2-resident, 1.6MB).
// ---------------------------------------------------------------------------
__global__ __launch_bounds__(256) void edge_aggregate128(const int* __restrict__ src,
                                                         const int* __restrict__ dst,
                                                         const float* __restrict__ el,
                                                         const float* __restrict__ er,
                                                         const float* __restrict__ den,
                                                         const float* __restrict__ feat,
                                                         float* __restrict__ acc,
                                                         int nE) {
    int gid  = blockIdx.x * blockDim.x + threadIdx.x;
    int e    = gid >> 6;
    int lane = gid & 63;
    if (e >= nE) return;
    int s = src[e], d = dst[e];
    int idx = lane * 2;
    int h   = idx >> 5;
    float v = el[s * 4 + h] + er[d * 4 + h];
    v = v > 0.f ? v : NEG_SLOPE * v;
    float alpha = expf(v) / den[d * 4 + h];
    float2 f = *(const float2*)(feat + (size_t)s * 128 + idx);
    atomicAdd(acc + (size_t)d * 128 + idx,     f.x * alpha);
    atomicAdd(acc + (size_t)d * 128 + idx + 1, f.y * alpha);
}

// ---------------------------------------------------------------------------
// Edge pass B for layer 2 (H=1, C=16): 4 threads per edge, float4 each.
// ---------------------------------------------------------------------------
__global__ __launch_bounds__(256) void edge_aggregate16(const int* __restrict__ src,
                                                        const int* __restrict__ dst,
                                                        const float* __restrict__ el,
                                                        const float* __restrict__ er,
                                                        const float* __restrict__ den,
                                                        const float* __restrict__ feat,
                                                        float* __restrict__ acc,
                                                        int nE) {
    int gid = blockIdx.x * blockDim.x + threadIdx.x;
    int e   = gid >> 2;
    int p   = gid & 3;
    if (e >= nE) return;
    int s = src[e], d = dst[e];
    float v = el[s] + er[d];
    v = v > 0.f ? v : NEG_SLOPE * v;
    float alpha = expf(v) / den[d];
    float4 f = *(const float4*)(feat + (size_t)s * 16 + p * 4);
    float* o = acc + (size_t)d * 16 + p * 4;
    atomicAdd(o,     f.x * alpha);
    atomicAdd(o + 1, f.y * alpha);
    atomicAdd(o + 2, f.z * alpha);
    atomicAdd(o + 3, f.w * alpha);
}

// ---------------------------------------------------------------------------
// Epilogues. relu(elu(x)) == relu(x), so hidden layers just need relu(+res).
// ---------------------------------------------------------------------------
__global__ __launch_bounds__(256) void relu_res(const float* __restrict__ acc,
                                                const float* __restrict__ res,
                                                float* __restrict__ out, int n4) {
    int g = blockIdx.x * blockDim.x + threadIdx.x;
    if (g >= n4) return;
    float4 a = ((const float4*)acc)[g];
    if (res) {
        float4 r = ((const float4*)res)[g];
        a.x += r.x; a.y += r.y; a.z += r.z; a.w += r.w;
    }
    a.x = fmaxf(a.x, 0.f);
    a.y = fmaxf(a.y, 0.f);
    a.z = fmaxf(a.z, 0.f);
    a.w = fmaxf(a.w, 0.f);
    ((float4*)out)[g] = a;
}

__global__ __launch_bounds__(256) void add_out(const float* __restrict__ acc,
                                               const float* __restrict__ res,
                                               float* __restrict__ out, int n4) {
    int g = blockIdx.x * blockDim.x + threadIdx.x;
    if (g >= n4) return;
    float4 a = ((const float4*)acc)[g];
    float4 r = ((const float4*)res)[g];
    a.x += r.x; a.y += r.y; a.z += r.z; a.w += r.w;
    ((float4*)out)[g] = a;
}

// ---------------------------------------------------------------------------
extern "C" void kernel_launch(void* const* d_in, const int* in_sizes, int n_in,
                              void* d_out, int out_size, void* d_ws, size_t ws_size,
                              hipStream_t stream) {
    const float* inputs = (const float*)d_in[0];
    const int*   src    = (const int*)d_in[1];
    const int*   dst    = (const int*)d_in[2];
    const float* W0     = (const float*)d_in[3];
    const float* al0    = (const float*)d_in[4];
    const float* ar0    = (const float*)d_in[5];
    const float* W1     = (const float*)d_in[6];
    const float* al1    = (const float*)d_in[7];
    const float* ar1    = (const float*)d_in[8];
    const float* W2     = (const float*)d_in[9];
    const float* al2    = (const float*)d_in[10];
    const float* ar2    = (const float*)d_in[11];
    const float* resW2  = (const float*)d_in[12];
    float* out = (float*)d_out;

    float* ws = (float*)d_ws;
    const size_t NF = (size_t)N_NODES * 128;
    float* feat = ws;                 // N*128
    float* acc  = ws + NF;            // N*128
    float* hbuf = ws + 2 * NF;        // N*128
    float* el   = ws + 3 * NF;        // N*4
    float* er   = el + N_NODES * 4;   // N*4
    float* den  = er + N_NODES * 4;   // N*4
    float* feat2 = feat;              // N*16 (within feat buffer)
    float* res2  = feat + (size_t)N_NODES * 16;  // N*16

    dim3 blk(256);
    int gemmGrid  = (N_NODES + 63) / 64;
    int edgeGrid  = (N_EDGES + 255) / 256;
    int aggGrid   = (N_EDGES * 64) / 256;           // wave per edge
    int agg16Grid = (N_EDGES * 4 + 255) / 256;      // 4 threads per edge
    int nodeGrid4 = ((int)(NF / 4) + 255) / 256;

    // ---------------- layer 0 ----------------
    gemm_feat<128><<<gemmGrid, blk, 0, stream>>>(inputs, W0, feat, N_NODES);
    eler_kernel<<<(N_NODES * 4 + 255) / 256, blk, 0, stream>>>(feat, al0, ar0, el, er,
                                                               N_NODES * 4, 4, 32);
    hipMemsetAsync(den, 0, (size_t)N_NODES * 4 * sizeof(float), stream);
    hipMemsetAsync(acc, 0, NF * sizeof(float), stream);
    edge_softmax_den<4><<<edgeGrid, blk, 0, stream>>>(src, dst, el, er, den, N_EDGES);
    edge_aggregate128<<<aggGrid, blk, 0, stream>>>(src, dst, el, er, den, feat, acc, N_EDGES);
    relu_res<<<nodeGrid4, blk, 0, stream>>>(acc, nullptr, hbuf, (int)(NF / 4));

    // ---------------- layer 1 ----------------
    gemm_feat<128><<<gemmGrid, blk, 0, stream>>>(hbuf, W1, feat, N_NODES);
    eler_kernel<<<(N_NODES * 4 + 255) / 256, blk, 0, stream>>>(feat, al1, ar1, el, er,
                                                               N_NODES * 4, 4, 32);
    hipMemsetAsync(den, 0, (size_t)N_NODES * 4 * sizeof(float), stream);
    hipMemsetAsync(acc, 0, NF * sizeof(float), stream);
    edge_softmax_den<4><<<edgeGrid, blk, 0, stream>>>(src, dst, el, er, den, N_EDGES);
    edge_aggregate128<<<aggGrid, blk, 0, stream>>>(src, dst, el, er, den, feat, acc, N_EDGES);
    relu_res<<<nodeGrid4, blk, 0, stream>>>(acc, hbuf, hbuf, (int)(NF / 4));

    // ---------------- layer 2 ----------------
    gemm_feat<16><<<gemmGrid, blk, 0, stream>>>(hbuf, W2, feat2, N_NODES);
    gemm_feat<16><<<gemmGrid, blk, 0, stream>>>(hbuf, resW2, res2, N_NODES);
    eler_kernel<<<(N_NODES + 255) / 256, blk, 0, stream>>>(feat2, al2, ar2, el, er,
                                                           N_NODES, 1, 16);
    hipMemsetAsync(den, 0, (size_t)N_NODES * sizeof(float), stream);
    hipMemsetAsync(acc, 0, (size_t)N_NODES * 16 * sizeof(float), stream);
    edge_softmax_den<1><<<edgeGrid, blk, 0, stream>>>(src, dst, el, er, den, N_EDGES);
    edge_aggregate16<<<agg16Grid, blk, 0, stream>>>(src, dst, el, er, den, feat2, acc, N_EDGES);
    add_out<<<(N_NODES * 16 / 4 + 255) / 256, blk, 0, stream>>>(acc, res2, out,
                                                                N_NODES * 16 / 4);
}

// Round 2
// 1136.082 us; speedup vs baseline: 3.5611x; 3.5611x over previous
//
#include <hip/hip_runtime.h>

#define N_NODES 100000
#define N_EDGES 1600000
#define IN_F    128
#define NEG_SLOPE 0.2f

// ---------------------------------------------------------------------------
// GEMM: out(nrows x F) = A(nrows x 128) @ W(128 x F)
// ---------------------------------------------------------------------------
template<int F>
__global__ __launch_bounds__(256) void gemm_feat(const float* __restrict__ A,
                                                 const float* __restrict__ W,
                                                 float* __restrict__ out,
                                                 int nrows) {
    constexpr int BM  = 64;
    constexpr int CG  = F / 4;
    constexpr int RPT = (BM * CG) / 256;
    __shared__ float sH[BM][IN_F];

    const int t    = threadIdx.x;
    const int row0 = blockIdx.x * BM;

#pragma unroll
    for (int i = 0; i < (BM * IN_F) / (256 * 4); ++i) {
        int e4 = i * 256 + t;
        int r  = (e4 * 4) >> 7;
        int c  = (e4 * 4) & 127;
        float4 v = make_float4(0.f, 0.f, 0.f, 0.f);
        int gr = row0 + r;
        if (gr < nrows) v = *(const float4*)(A + (size_t)gr * IN_F + c);
        *(float4*)(&sH[r][c]) = v;
    }
    __syncthreads();

    const int tx  = t % CG;
    const int ty  = t / CG;
    const int col = tx * 4;

    float4 acc[RPT];
#pragma unroll
    for (int i = 0; i < RPT; ++i) acc[i] = make_float4(0.f, 0.f, 0.f, 0.f);

    for (int k = 0; k < IN_F; ++k) {
        float4 b = *(const float4*)(W + k * F + col);
#pragma unroll
        for (int i = 0; i < RPT; ++i) {
            float a = sH[ty * RPT + i][k];
            acc[i].x += a * b.x;
            acc[i].y += a * b.y;
            acc[i].z += a * b.z;
            acc[i].w += a * b.w;
        }
    }

#pragma unroll
    for (int i = 0; i < RPT; ++i) {
        int r = row0 + ty * RPT + i;
        if (r < nrows) *(float4*)(out + (size_t)r * F + col) = acc[i];
    }
}

// ---------------------------------------------------------------------------
// el/er per (node,head)
// ---------------------------------------------------------------------------
__global__ __launch_bounds__(256) void eler_kernel(const float* __restrict__ feat,
                                                   const float* __restrict__ al,
                                                   const float* __restrict__ ar,
                                                   float* __restrict__ el,
                                                   float* __restrict__ er,
                                                   int nh_total, int H, int dim) {
    int g = blockIdx.x * blockDim.x + threadIdx.x;
    if (g >= nh_total) return;
    const float* f  = feat + (size_t)g * dim;
    const float* a1 = al + (g % H) * dim;
    const float* a2 = ar + (g % H) * dim;
    float s1 = 0.f, s2 = 0.f;
    for (int d = 0; d < dim; d += 4) {
        float4 v = *(const float4*)(f + d);
        float4 x = *(const float4*)(a1 + d);
        float4 y = *(const float4*)(a2 + d);
        s1 += v.x * x.x + v.y * x.y + v.z * x.z + v.w * x.w;
        s2 += v.x * y.x + v.y * y.y + v.z * y.z + v.w * y.w;
    }
    el[g] = s1;
    er[g] = s2;
}

// ---------------------------------------------------------------------------
// CSR build: degree count -> exclusive scan (hierarchical) -> scatter
// ---------------------------------------------------------------------------
__global__ __launch_bounds__(256) void deg_count(const int* __restrict__ dst,
                                                 int* __restrict__ deg, int nE) {
    int e = blockIdx.x * blockDim.x + threadIdx.x;
    if (e >= nE) return;
    atomicAdd(&deg[dst[e]], 1);
}

__global__ __launch_bounds__(256) void scan_blocks(const int* __restrict__ deg,
                                                   int* __restrict__ rowptr,
                                                   int* __restrict__ bsum, int n) {
    __shared__ int s[256];
    int t = threadIdx.x;
    int i = blockIdx.x * 256 + t;
    int v = (i < n) ? deg[i] : 0;
    s[t] = v;
    __syncthreads();
#pragma unroll
    for (int off = 1; off < 256; off <<= 1) {
        int x = (t >= off) ? s[t - off] : 0;
        __syncthreads();
        s[t] += x;
        __syncthreads();
    }
    if (i < n) rowptr[i] = s[t] - v;       // exclusive within block
    if (t == 255) bsum[blockIdx.x] = s[255];
}

__global__ __launch_bounds__(512) void scan_sums(int* __restrict__ bsum, int nb) {
    __shared__ int s[512];
    int t = threadIdx.x;
    int v = (t < nb) ? bsum[t] : 0;
    s[t] = v;
    __syncthreads();
#pragma unroll
    for (int off = 1; off < 512; off <<= 1) {
        int x = (t >= off) ? s[t - off] : 0;
        __syncthreads();
        s[t] += x;
        __syncthreads();
    }
    if (t < nb) bsum[t] = s[t] - v;        // exclusive over block sums
}

__global__ __launch_bounds__(256) void scan_add(int* __restrict__ rowptr,
                                                const int* __restrict__ bsum, int n) {
    int i = blockIdx.x * 256 + threadIdx.x;
    if (i < n) rowptr[i] += bsum[blockIdx.x];
}

__global__ __launch_bounds__(256) void scatter_edges(const int* __restrict__ src,
                                                     const int* __restrict__ dst,
                                                     const int* __restrict__ rowptr,
                                                     int* __restrict__ fill,
                                                     int* __restrict__ sorted_src, int nE) {
    int e = blockIdx.x * blockDim.x + threadIdx.x;
    if (e >= nE) return;
    int d = dst[e];
    int pos = rowptr[d] + atomicAdd(&fill[d], 1);
    sorted_src[pos] = src[e];
}

// ---------------------------------------------------------------------------
// Pull aggregation, H=4, D=32 (128 feats). One block (256 thr) per dst node.
// Stages <=64 edges' weights in LDS (wave 0), accumulates den without atomics,
// then all threads gather feat[src] coalesced. Fused /den + residual + relu.
// ---------------------------------------------------------------------------
__global__ __launch_bounds__(256) void gat_agg128(const int* __restrict__ rowptr,
                                                  const int* __restrict__ deg,
                                                  const int* __restrict__ sorted_src,
                                                  const float* __restrict__ el,
                                                  const float* __restrict__ er,
                                                  const float* __restrict__ feat,
                                                  const float* __restrict__ res,
                                                  float* __restrict__ out) {
    __shared__ int   sS[64];
    __shared__ float sW[64][4];
    __shared__ float sDen[4];
    __shared__ float sAcc[256];

    const int d  = blockIdx.x;
    const int t  = threadIdx.x;
    const int f  = t & 127;
    const int half = t >> 7;
    const int h  = f >> 5;
    const int dg = deg[d];
    const int r0 = rowptr[d];

    float denl[4] = {0.f, 0.f, 0.f, 0.f};
    float accp = 0.f;

    for (int base = 0; base < dg; base += 64) {
        int m = dg - base; if (m > 64) m = 64;
        if (t < m) {
            int s = sorted_src[r0 + base + t];
            sS[t] = s;
#pragma unroll
            for (int hh = 0; hh < 4; ++hh) {
                float v = el[s * 4 + hh] + er[d * 4 + hh];
                v = v > 0.f ? v : NEG_SLOPE * v;
                float w = __expf(v);
                sW[t][hh] = w;
                denl[hh] += w;
            }
        }
        __syncthreads();
        for (int i = half; i < m; i += 2)
            accp += sW[i][h] * feat[(size_t)sS[i] * 128 + f];
        __syncthreads();
    }

    // den reduce across wave 0
    if (t < 64) {
#pragma unroll
        for (int hh = 0; hh < 4; ++hh) {
            float v = denl[hh];
            for (int off = 32; off > 0; off >>= 1) v += __shfl_down(v, off);
            if (t == 0) sDen[hh] = v;
        }
    }
    sAcc[t] = accp;
    __syncthreads();

    if (t < 128) {
        float total = sAcc[t] + sAcc[t + 128];
        float dd = sDen[t >> 5];
        float scale = dd > 0.f ? 1.f / dd : 0.f;
        float o = total * scale;
        if (res) o += res[(size_t)d * 128 + t];
        o = fmaxf(o, 0.f);                         // relu(elu(x)) == relu(x)
        out[(size_t)d * 128 + t] = o;
    }
}

// ---------------------------------------------------------------------------
// Pull aggregation, H=1, C=16. One wave per node (4 nodes per block).
// All staging via shuffles (no LDS, no syncthreads). Fused /den + res2.
// ---------------------------------------------------------------------------
__global__ __launch_bounds__(256) void gat_agg16(const int* __restrict__ rowptr,
                                                 const int* __restrict__ deg,
                                                 const int* __restrict__ sorted_src,
                                                 const float* __restrict__ el,
                                                 const float* __restrict__ er,
                                                 const float* __restrict__ feat,
                                                 const float* __restrict__ res,
                                                 float* __restrict__ out, int n) {
    const int t    = threadIdx.x;
    const int nd   = blockIdx.x * 4 + (t >> 6);
    const int lane = t & 63;
    if (nd >= n) return;

    const int f = lane & 15;
    const int q = lane >> 4;
    const int dg = deg[nd];
    const int r0 = rowptr[nd];
    const float erd = er[nd];

    float acc = 0.f, den = 0.f;

    for (int base = 0; base < dg; base += 64) {
        int m = dg - base; if (m > 64) m = 64;
        int s = 0; float w = 0.f;
        if (lane < m) {
            s = sorted_src[r0 + base + lane];
            float v = el[s] + erd;
            v = v > 0.f ? v : NEG_SLOPE * v;
            w = __expf(v);
        }
        den += w;
#pragma unroll
        for (int j = 0; j < 16; ++j) {
            int idx = q * 16 + j;
            float wi = __shfl(w, idx);
            int   si = __shfl(s, idx);
            if (idx < m) acc += wi * feat[si * 16 + f];
        }
    }

    for (int off = 32; off > 0; off >>= 1) den += __shfl_down(den, off);
    den = __shfl(den, 0);

    acc += __shfl_down(acc, 32);
    acc += __shfl_down(acc, 16);

    if (lane < 16) {
        float scale = den > 0.f ? 1.f / den : 0.f;
        out[nd * 16 + f] = acc * scale + res[nd * 16 + f];
    }
}

// ---------------------------------------------------------------------------
extern "C" void kernel_launch(void* const* d_in, const int* in_sizes, int n_in,
                              void* d_out, int out_size, void* d_ws, size_t ws_size,
                              hipStream_t stream) {
    const float* inputs = (const float*)d_in[0];
    const int*   src    = (const int*)d_in[1];
    const int*   dst    = (const int*)d_in[2];
    const float* W0     = (const float*)d_in[3];
    const float* al0    = (const float*)d_in[4];
    const float* ar0    = (const float*)d_in[5];
    const float* W1     = (const float*)d_in[6];
    const float* al1    = (const float*)d_in[7];
    const float* ar1    = (const float*)d_in[8];
    const float* W2     = (const float*)d_in[9];
    const float* al2    = (const float*)d_in[10];
    const float* ar2    = (const float*)d_in[11];
    const float* resW2  = (const float*)d_in[12];
    float* out = (float*)d_out;

    const size_t NF = (size_t)N_NODES * 128;
    float* ws   = (float*)d_ws;
    float* feat = ws;                       // N*128
    float* hbuf = ws + NF;                  // N*128
    float* el   = ws + 2 * NF;              // N*4
    float* er   = el + (size_t)N_NODES * 4; // N*4
    float* feat2 = er + (size_t)N_NODES * 4;          // N*16
    float* res2  = feat2 + (size_t)N_NODES * 16;      // N*16

    int* iws        = (int*)(res2 + (size_t)N_NODES * 16);
    int* deg        = iws;                  // N
    int* rowptr     = iws + N_NODES;        // N
    int* fill       = iws + 2 * N_NODES;    // N
    int* bsum       = iws + 3 * N_NODES;    // 512
    int* sorted_src = iws + 3 * N_NODES + 512;  // E

    dim3 blk(256);
    int gemmGrid = (N_NODES + 63) / 64;
    int edgeGrid = (N_EDGES + 255) / 256;
    int NB       = (N_NODES + 255) / 256;   // 391 <= 512

    // ---------------- CSR build (graph shared by all 3 layers) -------------
    hipMemsetAsync(deg,  0, N_NODES * sizeof(int), stream);
    hipMemsetAsync(fill, 0, N_NODES * sizeof(int), stream);
    deg_count<<<edgeGrid, blk, 0, stream>>>(dst, deg, N_EDGES);
    scan_blocks<<<NB, blk, 0, stream>>>(deg, rowptr, bsum, N_NODES);
    scan_sums<<<1, 512, 0, stream>>>(bsum, NB);
    scan_add<<<NB, blk, 0, stream>>>(rowptr, bsum, N_NODES);
    scatter_edges<<<edgeGrid, blk, 0, stream>>>(src, dst, rowptr, fill, sorted_src, N_EDGES);

    // ---------------- layer 0 ----------------
    gemm_feat<128><<<gemmGrid, blk, 0, stream>>>(inputs, W0, feat, N_NODES);
    eler_kernel<<<(N_NODES * 4 + 255) / 256, blk, 0, stream>>>(feat, al0, ar0, el, er,
                                                               N_NODES * 4, 4, 32);
    gat_agg128<<<N_NODES, blk, 0, stream>>>(rowptr, deg, sorted_src, el, er, feat,
                                            nullptr, hbuf);

    // ---------------- layer 1 ----------------
    gemm_feat<128><<<gemmGrid, blk, 0, stream>>>(hbuf, W1, feat, N_NODES);
    eler_kernel<<<(N_NODES * 4 + 255) / 256, blk, 0, stream>>>(feat, al1, ar1, el, er,
                                                               N_NODES * 4, 4, 32);
    gat_agg128<<<N_NODES, blk, 0, stream>>>(rowptr, deg, sorted_src, el, er, feat,
                                            hbuf, hbuf);

    // ---------------- layer 2 ----------------
    gemm_feat<16><<<gemmGrid, blk, 0, stream>>>(hbuf, W2, feat2, N_NODES);
    gemm_feat<16><<<gemmGrid, blk, 0, stream>>>(hbuf, resW2, res2, N_NODES);
    eler_kernel<<<(N_NODES + 255) / 256, blk, 0, stream>>>(feat2, al2, ar2, el, er,
                                                           N_NODES, 1, 16);
    gat_agg16<<<(N_NODES + 3) / 4, blk, 0, stream>>>(rowptr, deg, sorted_src, el, er,
                                                     feat2, res2, out, N_NODES);
}

// Round 4
// 655.771 us; speedup vs baseline: 6.1695x; 1.7324x over previous
//
#include <hip/hip_runtime.h>

#define N_NODES 100000
#define N_EDGES 1600000
#define IN_F    128
#define NEG_SLOPE 0.2f

__device__ __forceinline__ float bf2f(unsigned short u) {
    return __uint_as_float(((unsigned int)u) << 16);
}

// f32 -> bf16 with round-to-nearest-even
__device__ __forceinline__ unsigned short f2bf(float f) {
    unsigned int u = __float_as_uint(f);
    u += 0x7FFFu + ((u >> 16) & 1u);
    return (unsigned short)(u >> 16);
}

// ---------------------------------------------------------------------------
// Fused GEMM for hidden layers: featb(bf16) = A(nrows x 128) @ W(128 x 128),
// with el/er (per node, per head) computed in the epilogue from the f32 accs.
// Block: 256 thr, 64 rows; thread = (ty=t/32 -> 8 rows) x (tx=t%32 -> 4 cols).
// ---------------------------------------------------------------------------
__global__ __launch_bounds__(256) void gemm128_fused(const float* __restrict__ A,
                                                     const float* __restrict__ W,
                                                     const float* __restrict__ al,
                                                     const float* __restrict__ ar,
                                                     unsigned short* __restrict__ featb,
                                                     float* __restrict__ el,
                                                     float* __restrict__ er,
                                                     int nrows) {
    __shared__ float sH[64][IN_F];
    const int t    = threadIdx.x;
    const int row0 = blockIdx.x * 64;

#pragma unroll
    for (int i = 0; i < 8; ++i) {
        int e4 = i * 256 + t;
        int r  = (e4 * 4) >> 7;
        int c  = (e4 * 4) & 127;
        float4 v = make_float4(0.f, 0.f, 0.f, 0.f);
        int gr = row0 + r;
        if (gr < nrows) v = *(const float4*)(A + (size_t)gr * IN_F + c);
        *(float4*)(&sH[r][c]) = v;
    }
    __syncthreads();

    const int tx  = t & 31;
    const int ty  = t >> 5;
    const int col = tx * 4;

    float4 acc[8];
#pragma unroll
    for (int i = 0; i < 8; ++i) acc[i] = make_float4(0.f, 0.f, 0.f, 0.f);

    for (int k = 0; k < IN_F; ++k) {
        float4 b = *(const float4*)(W + k * 128 + col);
#pragma unroll
        for (int i = 0; i < 8; ++i) {
            float a = sH[ty * 8 + i][k];
            acc[i].x += a * b.x;
            acc[i].y += a * b.y;
            acc[i].z += a * b.z;
            acc[i].w += a * b.w;
        }
    }

    const float4 alv = *(const float4*)(al + col);
    const float4 arv = *(const float4*)(ar + col);
    const int h = tx >> 3;                  // head owned by this 8-thread group

#pragma unroll
    for (int i = 0; i < 8; ++i) {
        int r = row0 + ty * 8 + i;
        float4 a = acc[i];
        if (r < nrows) {
            ushort4 u;
            u.x = f2bf(a.x);
            u.y = f2bf(a.y);
            u.z = f2bf(a.z);
            u.w = f2bf(a.w);
            *(ushort4*)(featb + (size_t)r * 128 + col) = u;
        }
        // el/er partial for this thread's 4 cols, reduce across the 8 threads
        float pel = a.x * alv.x + a.y * alv.y + a.z * alv.z + a.w * alv.w;
        float per = a.x * arv.x + a.y * arv.y + a.z * arv.z + a.w * arv.w;
        pel += __shfl_down(pel, 4); per += __shfl_down(per, 4);
        pel += __shfl_down(pel, 2); per += __shfl_down(per, 2);
        pel += __shfl_down(pel, 1); per += __shfl_down(per, 1);
        if ((tx & 7) == 0 && r < nrows) {
            el[r * 4 + h] = pel;
            er[r * 4 + h] = per;
        }
    }
}

// ---------------------------------------------------------------------------
// Dual GEMM for layer 2: feat2b(bf16) = A @ W2, res2(f32) = A @ resW2 (F=16),
// el/er (1 head) fused. Block: 256 thr, 64 rows; tx=t%8 (tx<4 -> W2 cols,
// tx>=4 -> resW2 cols), ty=t/8 -> 2 rows each.
// ---------------------------------------------------------------------------
__global__ __launch_bounds__(256) void gemm16_dual(const float* __restrict__ A,
                                                   const float* __restrict__ W2,
                                                   const float* __restrict__ resW2,
                                                   const float* __restrict__ al,
                                                   const float* __restrict__ ar,
                                                   unsigned short* __restrict__ feat2b,
                                                   float* __restrict__ res2,
                                                   float* __restrict__ el,
                                                   float* __restrict__ er,
                                                   int nrows) {
    __shared__ float sH[64][IN_F];
    const int t    = threadIdx.x;
    const int row0 = blockIdx.x * 64;

#pragma unroll
    for (int i = 0; i < 8; ++i) {
        int e4 = i * 256 + t;
        int r  = (e4 * 4) >> 7;
        int c  = (e4 * 4) & 127;
        float4 v = make_float4(0.f, 0.f, 0.f, 0.f);
        int gr = row0 + r;
        if (gr < nrows) v = *(const float4*)(A + (size_t)gr * IN_F + c);
        *(float4*)(&sH[r][c]) = v;
    }
    __syncthreads();

    const int tx   = t & 7;
    const int ty   = t >> 3;
    const bool isW = tx < 4;
    const int col  = (isW ? tx : tx - 4) * 4;
    const float* Wp = isW ? W2 : resW2;

    float4 acc[2];
    acc[0] = make_float4(0.f, 0.f, 0.f, 0.f);
    acc[1] = make_float4(0.f, 0.f, 0.f, 0.f);

    for (int k = 0; k < IN_F; ++k) {
        float4 b = *(const float4*)(Wp + k * 16 + col);
#pragma unroll
        for (int i = 0; i < 2; ++i) {
            float a = sH[ty * 2 + i][k];
            acc[i].x += a * b.x;
            acc[i].y += a * b.y;
            acc[i].z += a * b.z;
            acc[i].w += a * b.w;
        }
    }

    const float4 alv = isW ? *(const float4*)(al + col) : make_float4(0, 0, 0, 0);
    const float4 arv = isW ? *(const float4*)(ar + col) : make_float4(0, 0, 0, 0);

#pragma unroll
    for (int i = 0; i < 2; ++i) {
        int r = row0 + ty * 2 + i;
        float4 a = acc[i];
        if (isW) {
            if (r < nrows) {
                ushort4 u;
                u.x = f2bf(a.x);
                u.y = f2bf(a.y);
                u.z = f2bf(a.z);
                u.w = f2bf(a.w);
                *(ushort4*)(feat2b + (size_t)r * 16 + col) = u;
            }
            float pel = a.x * alv.x + a.y * alv.y + a.z * alv.z + a.w * alv.w;
            float per = a.x * arv.x + a.y * arv.y + a.z * arv.z + a.w * arv.w;
            pel += __shfl_down(pel, 2); per += __shfl_down(per, 2);
            pel += __shfl_down(pel, 1); per += __shfl_down(per, 1);
            if (tx == 0 && r < nrows) { el[r] = pel; er[r] = per; }
        } else if (r < nrows) {
            *(float4*)(res2 + (size_t)r * 16 + col) = a;
        }
    }
}

// ---------------------------------------------------------------------------
// CSR build
// ---------------------------------------------------------------------------
__global__ __launch_bounds__(256) void deg_count(const int* __restrict__ dst,
                                                 int* __restrict__ deg, int nE) {
    int e = blockIdx.x * blockDim.x + threadIdx.x;
    if (e >= nE) return;
    atomicAdd(&deg[dst[e]], 1);
}

__global__ __launch_bounds__(256) void scan_blocks(const int* __restrict__ deg,
                                                   int* __restrict__ rowptr,
                                                   int* __restrict__ bsum, int n) {
    __shared__ int s[256];
    int t = threadIdx.x;
    int i = blockIdx.x * 256 + t;
    int v = (i < n) ? deg[i] : 0;
    s[t] = v;
    __syncthreads();
#pragma unroll
    for (int off = 1; off < 256; off <<= 1) {
        int x = (t >= off) ? s[t - off] : 0;
        __syncthreads();
        s[t] += x;
        __syncthreads();
    }
    if (i < n) rowptr[i] = s[t] - v;
    if (t == 255) bsum[blockIdx.x] = s[255];
}

__global__ __launch_bounds__(512) void scan_sums(int* __restrict__ bsum, int nb) {
    __shared__ int s[512];
    int t = threadIdx.x;
    int v = (t < nb) ? bsum[t] : 0;
    s[t] = v;
    __syncthreads();
#pragma unroll
    for (int off = 1; off < 512; off <<= 1) {
        int x = (t >= off) ? s[t - off] : 0;
        __syncthreads();
        s[t] += x;
        __syncthreads();
    }
    if (t < nb) bsum[t] = s[t] - v;
}

__global__ __launch_bounds__(256) void scan_add(int* __restrict__ rowptr,
                                                const int* __restrict__ bsum, int n) {
    int i = blockIdx.x * 256 + threadIdx.x;
    if (i < n) rowptr[i] += bsum[blockIdx.x];
}

__global__ __launch_bounds__(256) void scatter_edges(const int* __restrict__ src,
                                                     const int* __restrict__ dst,
                                                     const int* __restrict__ rowptr,
                                                     int* __restrict__ fill,
                                                     int* __restrict__ sorted_src, int nE) {
    int e = blockIdx.x * blockDim.x + threadIdx.x;
    if (e >= nE) return;
    int d = dst[e];
    int pos = rowptr[d] + atomicAdd(&fill[d], 1);
    sorted_src[pos] = src[e];
}

// ---------------------------------------------------------------------------
// Pull aggregation, H=4, D=32 (128 feats), bf16 gathers. ONE WAVE PER NODE
// (4 nodes/block, no __syncthreads). Lane owns features (2*lane, 2*lane+1).
// Per 64-edge chunk: lanes stage src + 4 head-weights in per-wave LDS, then
// every lane walks all edges: ushort2 gather (256 B/edge coalesced) + fma.
// den accumulated per-lane (every lane sees every edge). Fused /den+res+relu.
// ---------------------------------------------------------------------------
__global__ __launch_bounds__(256) void gat_agg128(const int* __restrict__ rowptr,
                                                  const int* __restrict__ deg,
                                                  const int* __restrict__ sorted_src,
                                                  const float* __restrict__ el,
                                                  const float* __restrict__ er,
                                                  const unsigned short* __restrict__ featb,
                                                  const float* __restrict__ res,
                                                  float* __restrict__ out) {
    __shared__ int   sS[4][64];
    __shared__ float sW[4][64][4];

    const int wv   = threadIdx.x >> 6;
    const int lane = threadIdx.x & 63;
    const int nd   = blockIdx.x * 4 + wv;

    const int dg = deg[nd];
    const int r0 = rowptr[nd];
    const int h  = lane >> 4;
    const float4 er4 = *(const float4*)(er + nd * 4);

    float den = 0.f;
    float ax = 0.f, ay = 0.f;

    for (int base = 0; base < dg; base += 64) {
        int m = dg - base; if (m > 64) m = 64;
        if (lane < m) {
            int s = sorted_src[r0 + base + lane];
            sS[wv][lane] = s;
            float4 e4 = *(const float4*)(el + s * 4);
            float4 w;
            float v;
            v = e4.x + er4.x; v = v > 0.f ? v : NEG_SLOPE * v; w.x = __expf(v);
            v = e4.y + er4.y; v = v > 0.f ? v : NEG_SLOPE * v; w.y = __expf(v);
            v = e4.z + er4.z; v = v > 0.f ? v : NEG_SLOPE * v; w.z = __expf(v);
            v = e4.w + er4.w; v = v > 0.f ? v : NEG_SLOPE * v; w.w = __expf(v);
            *(float4*)(&sW[wv][lane][0]) = w;
        }
        // wave-synchronous: same wave wrote LDS, lgkmcnt ordering suffices
        for (int i = 0; i < m; ++i) {
            int s   = sS[wv][i];
            float w = sW[wv][i][h];
            den += w;
            ushort2 u = *(const ushort2*)(featb + (size_t)s * 128 + lane * 2);
            ax += w * bf2f(u.x);
            ay += w * bf2f(u.y);
        }
    }

    float scale = den > 0.f ? 1.f / den : 0.f;
    float ox = ax * scale, oy = ay * scale;
    size_t o0 = (size_t)nd * 128 + lane * 2;
    if (res) { ox += res[o0]; oy += res[o0 + 1]; }
    ox = fmaxf(ox, 0.f);
    oy = fmaxf(oy, 0.f);
    float2 o = make_float2(ox, oy);
    *(float2*)(out + o0) = o;
}

// ---------------------------------------------------------------------------
// Pull aggregation, H=1, C=16, bf16 gathers. Wave per node, shuffle staging.
// ---------------------------------------------------------------------------
__global__ __launch_bounds__(256) void gat_agg16(const int* __restrict__ rowptr,
                                                 const int* __restrict__ deg,
                                                 const int* __restrict__ sorted_src,
                                                 const float* __restrict__ el,
                                                 const float* __restrict__ er,
                                                 const unsigned short* __restrict__ feat2b,
                                                 const float* __restrict__ res,
                                                 float* __restrict__ out, int n) {
    const int t    = threadIdx.x;
    const int nd   = blockIdx.x * 4 + (t >> 6);
    const int lane = t & 63;
    if (nd >= n) return;

    const int f = lane & 15;
    const int q = lane >> 4;
    const int dg = deg[nd];
    const int r0 = rowptr[nd];
    const float erd = er[nd];

    float acc = 0.f, den = 0.f;

    for (int base = 0; base < dg; base += 64) {
        int m = dg - base; if (m > 64) m = 64;
        int s = 0; float w = 0.f;
        if (lane < m) {
            s = sorted_src[r0 + base + lane];
            float v = el[s] + erd;
            v = v > 0.f ? v : NEG_SLOPE * v;
            w = __expf(v);
        }
        den += w;
#pragma unroll
        for (int j = 0; j < 16; ++j) {
            int idx = q * 16 + j;
            float wi = __shfl(w, idx);
            int   si = __shfl(s, idx);
            if (idx < m) acc += wi * bf2f(feat2b[si * 16 + f]);
        }
    }

    for (int off = 32; off > 0; off >>= 1) den += __shfl_down(den, off);
    den = __shfl(den, 0);

    acc += __shfl_down(acc, 32);
    acc += __shfl_down(acc, 16);

    if (lane < 16) {
        float scale = den > 0.f ? 1.f / den : 0.f;
        out[nd * 16 + f] = acc * scale + res[nd * 16 + f];
    }
}

// ---------------------------------------------------------------------------
extern "C" void kernel_launch(void* const* d_in, const int* in_sizes, int n_in,
                              void* d_out, int out_size, void* d_ws, size_t ws_size,
                              hipStream_t stream) {
    const float* inputs = (const float*)d_in[0];
    const int*   src    = (const int*)d_in[1];
    const int*   dst    = (const int*)d_in[2];
    const float* W0     = (const float*)d_in[3];
    const float* al0    = (const float*)d_in[4];
    const float* ar0    = (const float*)d_in[5];
    const float* W1     = (const float*)d_in[6];
    const float* al1    = (const float*)d_in[7];
    const float* ar1    = (const float*)d_in[8];
    const float* W2     = (const float*)d_in[9];
    const float* al2    = (const float*)d_in[10];
    const float* ar2    = (const float*)d_in[11];
    const float* resW2  = (const float*)d_in[12];
    float* out = (float*)d_out;

    const size_t NF = (size_t)N_NODES * 128;
    float* ws   = (float*)d_ws;
    float* hbuf = ws;                                  // N*128 f32
    float* el   = ws + NF;                             // N*4
    float* er   = el + (size_t)N_NODES * 4;            // N*4
    float* res2 = er + (size_t)N_NODES * 4;            // N*16
    unsigned short* featb  = (unsigned short*)(res2 + (size_t)N_NODES * 16);  // N*128 bf16
    unsigned short* feat2b = featb + NF;                                      // N*16 bf16
    int* iws        = (int*)(feat2b + (size_t)N_NODES * 16);
    int* deg        = iws;
    int* rowptr     = iws + N_NODES;
    int* fill       = iws + 2 * N_NODES;
    int* bsum       = iws + 3 * N_NODES;
    int* sorted_src = iws + 3 * N_NODES + 512;

    dim3 blk(256);
    int gemmGrid = (N_NODES + 63) / 64;
    int edgeGrid = (N_EDGES + 255) / 256;
    int NB       = (N_NODES + 255) / 256;
    int aggGrid  = N_NODES / 4;        // 25000, exact

    // ---------------- CSR build (graph shared by all 3 layers) -------------
    hipMemsetAsync(deg,  0, N_NODES * sizeof(int), stream);
    hipMemsetAsync(fill, 0, N_NODES * sizeof(int), stream);
    deg_count<<<edgeGrid, blk, 0, stream>>>(dst, deg, N_EDGES);
    scan_blocks<<<NB, blk, 0, stream>>>(deg, rowptr, bsum, N_NODES);
    scan_sums<<<1, 512, 0, stream>>>(bsum, NB);
    scan_add<<<NB, blk, 0, stream>>>(rowptr, bsum, N_NODES);
    scatter_edges<<<edgeGrid, blk, 0, stream>>>(src, dst, rowptr, fill, sorted_src, N_EDGES);

    // ---------------- layer 0 ----------------
    gemm128_fused<<<gemmGrid, blk, 0, stream>>>(inputs, W0, al0, ar0, featb, el, er, N_NODES);
    gat_agg128<<<aggGrid, blk, 0, stream>>>(rowptr, deg, sorted_src, el, er, featb,
                                            nullptr, hbuf);

    // ---------------- layer 1 ----------------
    gemm128_fused<<<gemmGrid, blk, 0, stream>>>(hbuf, W1, al1, ar1, featb, el, er, N_NODES);
    gat_agg128<<<aggGrid, blk, 0, stream>>>(rowptr, deg, sorted_src, el, er, featb,
                                            hbuf, hbuf);

    // ---------------- layer 2 ----------------
    gemm16_dual<<<gemmGrid, blk, 0, stream>>>(hbuf, W2, resW2, al2, ar2, feat2b, res2,
                                              el, er, N_NODES);
    gat_agg16<<<aggGrid, blk, 0, stream>>>(rowptr, deg, sorted_src, el, er, feat2b,
                                           res2, out, N_NODES);
}